// Round 6
// baseline (44.610 us; speedup 1.0000x reference)
//
#include <hip/hip_runtime.h>
#include <math.h>

#define QN 32
#define SN 128
#define EN 256
#define BN 64
#define SCALE_F 20.0f
#define NB 1536     // total blocks: 1024 edq + 512 xy

// ws layout (floats): edq_part[QN*32] | xy_part[8*QN*BN] | counter (1 uint)
//
// Single-kernel design. Round-4 lesson: per-block __threadfence() (agent
// release -> L2 writeback x1536) cost ~100us. Here ALL cross-block
// communication uses relaxed agent-scope atomics (cache-bypassing,
// write-through to the coherent point), ordered manually with
// s_waitcnt vmcnt(0) -- no release fences, no L2 maintenance.

__device__ __forceinline__ float l1_4(float4 a, float4 b) {
    float dx = a.x - b.x, dy = a.y - b.y, dz = a.z - b.z, dw = a.w - b.w;
    return (fabsf(dx) + fabsf(dy)) + (fabsf(dz) + fabsf(dw));
}

__device__ __forceinline__ void agent_store(float* p, float v) {
    __hip_atomic_store(p, v, __ATOMIC_RELAXED, __HIP_MEMORY_SCOPE_AGENT);
}
__device__ __forceinline__ float agent_load(const float* p) {
    return __hip_atomic_load(p, __ATOMIC_RELAXED, __HIP_MEMORY_SCOPE_AGENT);
}

// Blocks [0,1024):  edq partials. q=bi&31, ic=(bi>>5)&3, jc=bi>>7.
//   Wave owns 8 i-rows (ibase=ic*32+wave*8), loops j in [jc*16, jc*16+16).
// Blocks [1024,1536): xy partials. bi2=bi-1024; q=bi2&31, bc=(bi2>>5)&1, sc=bi2>>6.
//   Wave owns 8 b-rows (bbase=bc*32+wave*8), loops s in [sc*16, sc*16+16).
// Last-arriving block (relaxed atomic counter) computes the CE loss.
__global__ __launch_bounds__(256) void kern_all(const float* __restrict__ A,
                                                const float* __restrict__ Cd,
                                                const int* __restrict__ M,
                                                float* __restrict__ edq_part,
                                                float* __restrict__ xy_part,
                                                unsigned int* __restrict__ counter,
                                                float* __restrict__ out) {
    const int bi   = blockIdx.x;
    const int wave = threadIdx.x >> 6, lane = threadIdx.x & 63;
    __shared__ float mf[SN];
    __shared__ float red[4];
    __shared__ unsigned int amLast;

    if (bi < 1024) {
        // ---------------- edq partial ----------------
        const int q = bi & 31, ic = (bi >> 5) & 3, jc = bi >> 7;
        if (threadIdx.x < SN) mf[threadIdx.x] = (float)M[q * SN + threadIdx.x];
        __syncthreads();

        const float* Aq = A + (size_t)q * SN * EN;
        const int ibase = ic * 32 + wave * 8;

        float4 ai[8];
#pragma unroll
        for (int k = 0; k < 8; ++k)
            ai[k] = *(const float4*)(Aq + (size_t)(ibase + k) * EN + lane * 4);

        float acc[8] = {0.f, 0.f, 0.f, 0.f, 0.f, 0.f, 0.f, 0.f};
        const int j0 = jc * 16;
#pragma unroll 4
        for (int j = j0; j < j0 + 16; ++j) {
            float4 aj = *(const float4*)(Aq + (size_t)j * EN + lane * 4);
            float  mj = mf[j];
#pragma unroll
            for (int k = 0; k < 8; ++k) acc[k] = fmaf(mj, l1_4(ai[k], aj), acc[k]);
        }

        float tot = 0.f;
#pragma unroll
        for (int k = 0; k < 8; ++k) tot = fmaf(mf[ibase + k], acc[k], tot);
#pragma unroll
        for (int off = 32; off; off >>= 1) tot += __shfl_down(tot, off, 64);
        if (lane == 0) red[wave] = tot;
        __syncthreads();
        if (threadIdx.x == 0)
            agent_store(&edq_part[q * 32 + ic * 8 + jc],
                        red[0] + red[1] + red[2] + red[3]);
    } else {
        // ---------------- xy partial ----------------
        const int bi2 = bi - 1024;
        const int q = bi2 & 31, bc = (bi2 >> 5) & 1, sc = bi2 >> 6;
        if (threadIdx.x < SN) mf[threadIdx.x] = (float)M[q * SN + threadIdx.x];
        __syncthreads();

        const int bbase = bc * 32 + wave * 8;
        float4 cb[8];
#pragma unroll
        for (int k = 0; k < 8; ++k)
            cb[k] = *(const float4*)(Cd + (size_t)(bbase + k) * EN + lane * 4);

        float acc[8] = {0.f, 0.f, 0.f, 0.f, 0.f, 0.f, 0.f, 0.f};
        const float* Aq = A + (size_t)q * SN * EN;
        const int s0 = sc * 16;
#pragma unroll 4
        for (int s = s0; s < s0 + 16; ++s) {
            float4 as = *(const float4*)(Aq + (size_t)s * EN + lane * 4);
            float  ms = mf[s];
#pragma unroll
            for (int k = 0; k < 8; ++k) acc[k] = fmaf(ms, l1_4(as, cb[k]), acc[k]);
        }

#pragma unroll
        for (int k = 0; k < 8; ++k) {
            float t = acc[k];
#pragma unroll
            for (int off = 32; off; off >>= 1) t += __shfl_down(t, off, 64);
            if (lane == 0)
                agent_store(&xy_part[(sc * QN + q) * BN + bbase + k], t);
        }
    }

    // ---- handshake: drain this wave's coherent stores, then count arrival ----
    asm volatile("s_waitcnt vmcnt(0)" ::: "memory");
    __syncthreads();
    if (threadIdx.x == 0) {
        unsigned int old = __hip_atomic_fetch_add(counter, 1u, __ATOMIC_RELAXED,
                                                  __HIP_MEMORY_SCOPE_AGENT);
        amLast = (old == NB - 1u) ? 1u : 0u;
    }
    __syncthreads();

    if (amLast) {
        // ---------------- loss (reads via coherent-point loads) ----------------
        float lsum = 0.f;
        for (int q = wave; q < QN; q += 4) {
            float mv = (float)M[q * SN + lane] + (float)M[q * SN + 64 + lane];
#pragma unroll
            for (int off = 32; off; off >>= 1) mv += __shfl_xor(mv, off, 64);
            float nv    = mv;
            float valid = fmaxf(nv, 1.f);
            float vp    = fmaxf(nv * nv, 1.f);

            float ednum = 0.f;
#pragma unroll
            for (int c = 0; c < 32; ++c) ednum += agent_load(&edq_part[q * 32 + c]);
            float edq = ednum / vp;

            float xv = 0.f;
#pragma unroll
            for (int sc = 0; sc < 8; ++sc)
                xv += agent_load(&xy_part[(sc * QN + q) * BN + lane]);

            float score = -SCALE_F * (2.f * xv / valid - edq);

            float mx = score;
#pragma unroll
            for (int off = 32; off; off >>= 1) mx = fmaxf(mx, __shfl_xor(mx, off, 64));
            float ex = __expf(score - mx);
#pragma unroll
            for (int off = 32; off; off >>= 1) ex += __shfl_xor(ex, off, 64);
            float lse  = mx + __logf(ex);
            float diag = __shfl(score, q, 64);
            lsum += lse - diag;
        }
        if (lane == 0) red[wave] = lsum;
        __syncthreads();
        if (threadIdx.x == 0)
            out[0] = (red[0] + red[1] + red[2] + red[3]) / (float)QN;
    }
}

extern "C" void kernel_launch(void* const* d_in, const int* in_sizes, int n_in,
                              void* d_out, int out_size, void* d_ws, size_t ws_size,
                              hipStream_t stream) {
    const float* A  = (const float*)d_in[0];   // anchors [Q,S,E] f32
    const float* Cd = (const float*)d_in[1];   // candidates [B,E] f32
    const int*   M  = (const int*)d_in[2];     // attention_mask [Q,S] i32
    float* out = (float*)d_out;

    float* edq_part = (float*)d_ws;                        // [QN*32]   = 1024 f
    float* xy_part  = edq_part + QN * 32;                  // [8*QN*BN] = 16384 f
    unsigned int* counter = (unsigned int*)(xy_part + 8 * QN * BN);

    hipMemsetAsync(counter, 0, sizeof(unsigned int), stream);
    kern_all<<<NB, 256, 0, stream>>>(A, Cd, M, edq_part, xy_part, counter, out);
}

// Round 7
// 31.442 us; speedup vs baseline: 1.4188x; 1.4188x over previous
//
#include <hip/hip_runtime.h>
#include <math.h>

#define QN 32
#define SN 128
#define EN 256
#define BN 64
#define SCALE_F 20.0f

// ws (floats): edq_part[QN*32] | xy_part[8*QN*BN] | loss_q[QN] | {qcnt[QN], done_cnt} (uints)
//
// Single kernel, DISTRIBUTED closure: per-q arrival counters (48 blocks each);
// the last block for q computes that q's softmax row inline; the last of the
// 32 q-closers sums loss_q[] in fixed order. No release fences (round-4
// lesson: agent release fence x1536 = ~100us of L2 maintenance). All
// cross-block traffic = relaxed agent-scope atomics ordered by vmcnt drains
// (mechanism validated in round 6).

__device__ __forceinline__ float l1_4(float4 a, float4 b) {
    float dx = a.x - b.x, dy = a.y - b.y, dz = a.z - b.z, dw = a.w - b.w;
    return (fabsf(dx) + fabsf(dy)) + (fabsf(dz) + fabsf(dw));
}

__device__ __forceinline__ void agent_store(float* p, float v) {
    __hip_atomic_store(p, v, __ATOMIC_RELAXED, __HIP_MEMORY_SCOPE_AGENT);
}
__device__ __forceinline__ float agent_load(const float* p) {
    return __hip_atomic_load(p, __ATOMIC_RELAXED, __HIP_MEMORY_SCOPE_AGENT);
}

// Blocks [0,1024):  edq partials. q=bi&31, ic=(bi>>5)&3, jc=bi>>7.
//   Wave owns 8 i-rows (ibase=ic*32+wave*8), loops j in [jc*16, jc*16+16).
// Blocks [1024,1536): xy partials. bi2=bi-1024; q=bi2&31, bc=(bi2>>5)&1, sc=bi2>>6.
//   Wave owns 8 b-rows (bbase=bc*32+wave*8), loops s in [sc*16, sc*16+16).
// Per q: 32 edq blocks + 16 xy blocks = 48 arrivals.
__global__ __launch_bounds__(256) void kern_all(const float* __restrict__ A,
                                                const float* __restrict__ Cd,
                                                const int* __restrict__ M,
                                                float* __restrict__ edq_part,
                                                float* __restrict__ xy_part,
                                                float* __restrict__ loss_q,
                                                unsigned int* __restrict__ qcnt,
                                                unsigned int* __restrict__ done_cnt,
                                                float* __restrict__ out) {
    const int bi   = blockIdx.x;
    const int wave = threadIdx.x >> 6, lane = threadIdx.x & 63;
    __shared__ float mf[SN];
    __shared__ float red[4];
    __shared__ unsigned int lastq;

    int q;
    if (bi < 1024) {
        // ---------------- edq partial ----------------
        const int ic = (bi >> 5) & 3, jc = bi >> 7;
        q = bi & 31;
        if (threadIdx.x < SN) mf[threadIdx.x] = (float)M[q * SN + threadIdx.x];
        __syncthreads();

        const float* Aq = A + (size_t)q * SN * EN;
        const int ibase = ic * 32 + wave * 8;

        float4 ai[8];
#pragma unroll
        for (int k = 0; k < 8; ++k)
            ai[k] = *(const float4*)(Aq + (size_t)(ibase + k) * EN + lane * 4);

        float acc[8] = {0.f, 0.f, 0.f, 0.f, 0.f, 0.f, 0.f, 0.f};
        const int j0 = jc * 16;
#pragma unroll 4
        for (int j = j0; j < j0 + 16; ++j) {
            float4 aj = *(const float4*)(Aq + (size_t)j * EN + lane * 4);
            float  mj = mf[j];
#pragma unroll
            for (int k = 0; k < 8; ++k) acc[k] = fmaf(mj, l1_4(ai[k], aj), acc[k]);
        }

        float tot = 0.f;
#pragma unroll
        for (int k = 0; k < 8; ++k) tot = fmaf(mf[ibase + k], acc[k], tot);
#pragma unroll
        for (int off = 32; off; off >>= 1) tot += __shfl_down(tot, off, 64);
        if (lane == 0) red[wave] = tot;
        __syncthreads();
        if (threadIdx.x == 0)
            agent_store(&edq_part[q * 32 + ic * 8 + jc],
                        red[0] + red[1] + red[2] + red[3]);
    } else {
        // ---------------- xy partial ----------------
        const int bi2 = bi - 1024;
        const int bc = (bi2 >> 5) & 1, sc = bi2 >> 6;
        q = bi2 & 31;
        if (threadIdx.x < SN) mf[threadIdx.x] = (float)M[q * SN + threadIdx.x];
        __syncthreads();

        const int bbase = bc * 32 + wave * 8;
        float4 cb[8];
#pragma unroll
        for (int k = 0; k < 8; ++k)
            cb[k] = *(const float4*)(Cd + (size_t)(bbase + k) * EN + lane * 4);

        float acc[8] = {0.f, 0.f, 0.f, 0.f, 0.f, 0.f, 0.f, 0.f};
        const float* Aq = A + (size_t)q * SN * EN;
        const int s0 = sc * 16;
#pragma unroll 4
        for (int s = s0; s < s0 + 16; ++s) {
            float4 as = *(const float4*)(Aq + (size_t)s * EN + lane * 4);
            float  ms = mf[s];
#pragma unroll
            for (int k = 0; k < 8; ++k) acc[k] = fmaf(ms, l1_4(as, cb[k]), acc[k]);
        }

#pragma unroll
        for (int k = 0; k < 8; ++k) {
            float t = acc[k];
#pragma unroll
            for (int off = 32; off; off >>= 1) t += __shfl_down(t, off, 64);
            if (lane == 0)
                agent_store(&xy_part[(sc * QN + q) * BN + bbase + k], t);
        }
    }

    // ---- arrival on THIS q's counter (48 contributors, 32 parallel lines) ----
    asm volatile("s_waitcnt vmcnt(0)" ::: "memory");
    __syncthreads();
    if (threadIdx.x == 0) {
        unsigned int old = __hip_atomic_fetch_add(&qcnt[q], 1u, __ATOMIC_RELAXED,
                                                  __HIP_MEMORY_SCOPE_AGENT);
        lastq = (old == 47u) ? 1u : 0u;
    }
    __syncthreads();

    if (lastq && wave == 0) {
        // ---------------- per-q closure (wave 0, 64 lanes, lane == b) ----------
        float ednum = (lane < 32) ? agent_load(&edq_part[q * 32 + lane]) : 0.f;
#pragma unroll
        for (int off = 32; off; off >>= 1) ednum += __shfl_xor(ednum, off, 64);

        float xv = 0.f;
#pragma unroll
        for (int sc = 0; sc < 8; ++sc)
            xv += agent_load(&xy_part[(sc * QN + q) * BN + lane]);

        float mv = mf[lane] + mf[64 + lane];   // mask row already staged for this q
#pragma unroll
        for (int off = 32; off; off >>= 1) mv += __shfl_xor(mv, off, 64);
        float valid = fmaxf(mv, 1.f);
        float vp    = fmaxf(mv * mv, 1.f);

        float score = -SCALE_F * (2.f * xv / valid - ednum / vp);

        float mx = score;
#pragma unroll
        for (int off = 32; off; off >>= 1) mx = fmaxf(mx, __shfl_xor(mx, off, 64));
        float ex = __expf(score - mx);
#pragma unroll
        for (int off = 32; off; off >>= 1) ex += __shfl_xor(ex, off, 64);
        float lse  = mx + __logf(ex);
        float diag = __shfl(score, q, 64);

        if (lane == 0) agent_store(&loss_q[q], lse - diag);
        asm volatile("s_waitcnt vmcnt(0)" ::: "memory");

        unsigned int old2 = 0u;
        if (lane == 0)
            old2 = __hip_atomic_fetch_add(done_cnt, 1u, __ATOMIC_RELAXED,
                                          __HIP_MEMORY_SCOPE_AGENT);
        old2 = __shfl(old2, 0, 64);

        if (old2 == QN - 1u) {
            // ---------------- final: fixed-order sum of 32 per-q losses --------
            float lv = (lane == 0) ? 0.f : 0.f;
            if (lane == 0) {
                float s = 0.f;
#pragma unroll
                for (int qq = 0; qq < QN; ++qq) s += agent_load(&loss_q[qq]);
                out[0] = s / (float)QN;
            }
            (void)lv;
        }
    }
}

extern "C" void kernel_launch(void* const* d_in, const int* in_sizes, int n_in,
                              void* d_out, int out_size, void* d_ws, size_t ws_size,
                              hipStream_t stream) {
    const float* A  = (const float*)d_in[0];   // anchors [Q,S,E] f32
    const float* Cd = (const float*)d_in[1];   // candidates [B,E] f32
    const int*   M  = (const int*)d_in[2];     // attention_mask [Q,S] i32
    float* out = (float*)d_out;

    float* edq_part = (float*)d_ws;                        // [QN*32]   = 1024 f
    float* xy_part  = edq_part + QN * 32;                  // [8*QN*BN] = 16384 f
    float* loss_q   = xy_part + 8 * QN * BN;               // [QN]      = 32 f
    unsigned int* qcnt     = (unsigned int*)(loss_q + QN); // [QN]
    unsigned int* done_cnt = qcnt + QN;                    // [1]

    hipMemsetAsync(qcnt, 0, (QN + 1) * sizeof(unsigned int), stream);
    kern_all<<<1536, 256, 0, stream>>>(A, Cd, M, edq_part, xy_part,
                                       loss_q, qcnt, done_cnt, out);
}

// Round 8
// 30.922 us; speedup vs baseline: 1.4427x; 1.0168x over previous
//
#include <hip/hip_runtime.h>
#include <math.h>

#define QN 32
#define SN 128
#define EN 256
#define BN 64
#define SCALE_F 20.0f
#define NT 20       // upper-triangle (i,j) tiles per q: 12 full + 8 diagonal
#define NB (QN * NT + 512)   // 640 edq blocks + 512 xy blocks

// ws (floats): edq_part[QN*NT] | xy_part[8*QN*BN] | loss_q[QN] | {qcnt[QN], done_cnt}
//
// Round-7 structure (per-q distributed closure, relaxed agent atomics,
// vmcnt-drain handshake — validated twice) + NEW: edq symmetry.
//   sum_{i,j} m_i m_j d_ij = 2 * sum_{j>i} m_i m_j d_ij   (diagonal d_ii = 0)
// Tiles: i-tile 32 x j-tile 16; keep only tiles with j-range >= i-range.
//   ti=0: tj 0..7 | ti=1: tj 2..7 | ti=2: tj 4..7 | ti=3: tj 6..7  (20 tiles)
// Diagonal tiles (tj>>1 == ti) mask per-row with wave-uniform (j > i) selects.

__device__ __forceinline__ float l1_4(float4 a, float4 b) {
    float dx = a.x - b.x, dy = a.y - b.y, dz = a.z - b.z, dw = a.w - b.w;
    return (fabsf(dx) + fabsf(dy)) + (fabsf(dz) + fabsf(dw));
}

__device__ __forceinline__ void agent_store(float* p, float v) {
    __hip_atomic_store(p, v, __ATOMIC_RELAXED, __HIP_MEMORY_SCOPE_AGENT);
}
__device__ __forceinline__ float agent_load(const float* p) {
    return __hip_atomic_load(p, __ATOMIC_RELAXED, __HIP_MEMORY_SCOPE_AGENT);
}

__global__ __launch_bounds__(256) void kern_all(const float* __restrict__ A,
                                                const float* __restrict__ Cd,
                                                const int* __restrict__ M,
                                                float* __restrict__ edq_part,
                                                float* __restrict__ xy_part,
                                                float* __restrict__ loss_q,
                                                unsigned int* __restrict__ qcnt,
                                                unsigned int* __restrict__ done_cnt,
                                                float* __restrict__ out) {
    const int bi   = blockIdx.x;
    const int wave = threadIdx.x >> 6, lane = threadIdx.x & 63;
    __shared__ float mf[SN];
    __shared__ float red[4];
    __shared__ unsigned int lastq;

    int q;
    if (bi < QN * NT) {
        // ---------------- edq partial (upper-triangle tile) ----------------
        const int t = bi >> 5;
        q = bi & 31;
        int ti, tj;
        if (t < 8)       { ti = 0; tj = t; }
        else if (t < 14) { ti = 1; tj = t - 6; }
        else if (t < 18) { ti = 2; tj = t - 10; }
        else             { ti = 3; tj = t - 12; }
        const bool diag = ((tj >> 1) == ti);

        if (threadIdx.x < SN) mf[threadIdx.x] = (float)M[q * SN + threadIdx.x];
        __syncthreads();

        const float* Aq = A + (size_t)q * SN * EN;
        const int ibase = ti * 32 + wave * 8;

        float4 ai[8];
#pragma unroll
        for (int k = 0; k < 8; ++k)
            ai[k] = *(const float4*)(Aq + (size_t)(ibase + k) * EN + lane * 4);

        float acc[8] = {0.f, 0.f, 0.f, 0.f, 0.f, 0.f, 0.f, 0.f};
        const int j0 = tj * 16;
        if (!diag) {
#pragma unroll 4
            for (int j = j0; j < j0 + 16; ++j) {
                float4 aj = *(const float4*)(Aq + (size_t)j * EN + lane * 4);
                float  mj = mf[j];
#pragma unroll
                for (int k = 0; k < 8; ++k) acc[k] = fmaf(mj, l1_4(ai[k], aj), acc[k]);
            }
        } else {
#pragma unroll 4
            for (int j = j0; j < j0 + 16; ++j) {
                float4 aj = *(const float4*)(Aq + (size_t)j * EN + lane * 4);
                float  mj = mf[j];
#pragma unroll
                for (int k = 0; k < 8; ++k) {
                    float w = (j > ibase + k) ? mj : 0.f;   // wave-uniform select
                    acc[k] = fmaf(w, l1_4(ai[k], aj), acc[k]);
                }
            }
        }

        float tot = 0.f;
#pragma unroll
        for (int k = 0; k < 8; ++k) tot = fmaf(mf[ibase + k], acc[k], tot);
#pragma unroll
        for (int off = 32; off; off >>= 1) tot += __shfl_down(tot, off, 64);
        if (lane == 0) red[wave] = tot;
        __syncthreads();
        if (threadIdx.x == 0)
            agent_store(&edq_part[q * NT + t],
                        red[0] + red[1] + red[2] + red[3]);
    } else {
        // ---------------- xy partial ----------------
        const int bi2 = bi - QN * NT;
        const int bc = (bi2 >> 5) & 1, sc = bi2 >> 6;
        q = bi2 & 31;
        if (threadIdx.x < SN) mf[threadIdx.x] = (float)M[q * SN + threadIdx.x];
        __syncthreads();

        const int bbase = bc * 32 + wave * 8;
        float4 cb[8];
#pragma unroll
        for (int k = 0; k < 8; ++k)
            cb[k] = *(const float4*)(Cd + (size_t)(bbase + k) * EN + lane * 4);

        float acc[8] = {0.f, 0.f, 0.f, 0.f, 0.f, 0.f, 0.f, 0.f};
        const float* Aq = A + (size_t)q * SN * EN;
        const int s0 = sc * 16;
#pragma unroll 4
        for (int s = s0; s < s0 + 16; ++s) {
            float4 as = *(const float4*)(Aq + (size_t)s * EN + lane * 4);
            float  ms = mf[s];
#pragma unroll
            for (int k = 0; k < 8; ++k) acc[k] = fmaf(ms, l1_4(as, cb[k]), acc[k]);
        }

#pragma unroll
        for (int k = 0; k < 8; ++k) {
            float t = acc[k];
#pragma unroll
            for (int off = 32; off; off >>= 1) t += __shfl_down(t, off, 64);
            if (lane == 0)
                agent_store(&xy_part[(sc * QN + q) * BN + bbase + k], t);
        }
    }

    // ---- arrival on THIS q's counter (36 contributors, 32 parallel lines) ----
    asm volatile("s_waitcnt vmcnt(0)" ::: "memory");
    __syncthreads();
    if (threadIdx.x == 0) {
        unsigned int old = __hip_atomic_fetch_add(&qcnt[q], 1u, __ATOMIC_RELAXED,
                                                  __HIP_MEMORY_SCOPE_AGENT);
        lastq = (old == (NT + 16 - 1)) ? 1u : 0u;
    }
    __syncthreads();

    if (lastq && wave == 0) {
        // ---------------- per-q closure (wave 0, 64 lanes, lane == b) ----------
        float ednum = (lane < NT) ? agent_load(&edq_part[q * NT + lane]) : 0.f;
#pragma unroll
        for (int off = 32; off; off >>= 1) ednum += __shfl_xor(ednum, off, 64);

        float xv = 0.f;
#pragma unroll
        for (int sc = 0; sc < 8; ++sc)
            xv += agent_load(&xy_part[(sc * QN + q) * BN + lane]);

        float mv = mf[lane] + mf[64 + lane];   // mask row already staged for this q
#pragma unroll
        for (int off = 32; off; off >>= 1) mv += __shfl_xor(mv, off, 64);
        float valid = fmaxf(mv, 1.f);
        float vp    = fmaxf(mv * mv, 1.f);

        // symmetry: full pair-sum = 2 * upper-triangle sum
        float score = -SCALE_F * (2.f * xv / valid - 2.f * ednum / vp);

        float mx = score;
#pragma unroll
        for (int off = 32; off; off >>= 1) mx = fmaxf(mx, __shfl_xor(mx, off, 64));
        float ex = __expf(score - mx);
#pragma unroll
        for (int off = 32; off; off >>= 1) ex += __shfl_xor(ex, off, 64);
        float lse  = mx + __logf(ex);
        float diag = __shfl(score, q, 64);

        if (lane == 0) agent_store(&loss_q[q], lse - diag);
        asm volatile("s_waitcnt vmcnt(0)" ::: "memory");

        unsigned int old2 = 0u;
        if (lane == 0)
            old2 = __hip_atomic_fetch_add(done_cnt, 1u, __ATOMIC_RELAXED,
                                          __HIP_MEMORY_SCOPE_AGENT);
        old2 = __shfl(old2, 0, 64);

        if (old2 == QN - 1u && lane == 0) {
            // ---------------- final: fixed-order sum of 32 per-q losses --------
            float s = 0.f;
#pragma unroll
            for (int qq = 0; qq < QN; ++qq) s += agent_load(&loss_q[qq]);
            out[0] = s / (float)QN;
        }
    }
}

extern "C" void kernel_launch(void* const* d_in, const int* in_sizes, int n_in,
                              void* d_out, int out_size, void* d_ws, size_t ws_size,
                              hipStream_t stream) {
    const float* A  = (const float*)d_in[0];   // anchors [Q,S,E] f32
    const float* Cd = (const float*)d_in[1];   // candidates [B,E] f32
    const int*   M  = (const int*)d_in[2];     // attention_mask [Q,S] i32
    float* out = (float*)d_out;

    float* edq_part = (float*)d_ws;                        // [QN*NT]   = 640 f
    float* xy_part  = edq_part + QN * NT;                  // [8*QN*BN] = 16384 f
    float* loss_q   = xy_part + 8 * QN * BN;               // [QN]      = 32 f
    unsigned int* qcnt     = (unsigned int*)(loss_q + QN); // [QN]
    unsigned int* done_cnt = qcnt + QN;                    // [1]

    hipMemsetAsync(qcnt, 0, (QN + 1) * sizeof(unsigned int), stream);
    kern_all<<<NB, 256, 0, stream>>>(A, Cd, M, edq_part, xy_part,
                                     loss_q, qcnt, done_cnt, out);
}

// Round 9
// 29.938 us; speedup vs baseline: 1.4901x; 1.0329x over previous
//
#include <hip/hip_runtime.h>
#include <math.h>

#define QN 32
#define SN 128
#define EN 256
#define BN 64
#define SCALE_F 20.0f
#define NT 20       // upper-triangle (i,j) tiles per q: 12 full + 8 diagonal
#define NB (QN * NT + 512)   // 640 edq blocks + 512 xy blocks

// ws (floats): edq_part[QN*NT] | xy_part[8*QN*BN] | loss_q[QN] | {qcnt[QN], done_cnt}
//
// Round-8 structure (per-q distributed closure, relaxed agent atomics,
// vmcnt-drain handshake, upper-tri symmetry) + NEW: all-loads-upfront.
// Each tile block issues mask + 8 i-rows + 16 j-rows (25 independent global
// loads) BEFORE any compute -> one latency exposure per block instead of
// interleaved load/compute groups (round-8 PMC: VALUBusy 27%, HBM ~1% =>
// stall-bound on serialized load round-trips).

__device__ __forceinline__ float l1_4(float4 a, float4 b) {
    float dx = a.x - b.x, dy = a.y - b.y, dz = a.z - b.z, dw = a.w - b.w;
    return (fabsf(dx) + fabsf(dy)) + (fabsf(dz) + fabsf(dw));
}

__device__ __forceinline__ void agent_store(float* p, float v) {
    __hip_atomic_store(p, v, __ATOMIC_RELAXED, __HIP_MEMORY_SCOPE_AGENT);
}
__device__ __forceinline__ float agent_load(const float* p) {
    return __hip_atomic_load(p, __ATOMIC_RELAXED, __HIP_MEMORY_SCOPE_AGENT);
}

__global__ __launch_bounds__(256) void kern_all(const float* __restrict__ A,
                                                const float* __restrict__ Cd,
                                                const int* __restrict__ M,
                                                float* __restrict__ edq_part,
                                                float* __restrict__ xy_part,
                                                float* __restrict__ loss_q,
                                                unsigned int* __restrict__ qcnt,
                                                unsigned int* __restrict__ done_cnt,
                                                float* __restrict__ out) {
    const int bi   = blockIdx.x;
    const int wave = threadIdx.x >> 6, lane = threadIdx.x & 63;
    __shared__ float mf[SN];
    __shared__ float red[4];
    __shared__ unsigned int lastq;

    int q;
    if (bi < QN * NT) {
        // ---------------- edq partial (upper-triangle tile) ----------------
        const int t = bi >> 5;
        q = bi & 31;
        int ti, tj;
        if (t < 8)       { ti = 0; tj = t; }
        else if (t < 14) { ti = 1; tj = t - 6; }
        else if (t < 18) { ti = 2; tj = t - 10; }
        else             { ti = 3; tj = t - 12; }
        const bool diag = ((tj >> 1) == ti);

        // issue mask load first (result used only at the mf write below)
        int mraw = (threadIdx.x < SN) ? M[q * SN + threadIdx.x] : 0;

        const float* Aq = A + (size_t)q * SN * EN;
        const int ibase = ti * 32 + wave * 8;
        const int j0 = tj * 16;

        // issue all 8 i-row loads
        float4 ai[8];
#pragma unroll
        for (int k = 0; k < 8; ++k)
            ai[k] = *(const float4*)(Aq + (size_t)(ibase + k) * EN + lane * 4);

        // issue all 16 j-row loads
        float4 jr[16];
#pragma unroll
        for (int jj = 0; jj < 16; ++jj)
            jr[jj] = *(const float4*)(Aq + (size_t)(j0 + jj) * EN + lane * 4);

        if (threadIdx.x < SN) mf[threadIdx.x] = (float)mraw;
        __syncthreads();

        float acc[8] = {0.f, 0.f, 0.f, 0.f, 0.f, 0.f, 0.f, 0.f};
        if (!diag) {
#pragma unroll
            for (int jj = 0; jj < 16; ++jj) {
                float mj = mf[j0 + jj];
#pragma unroll
                for (int k = 0; k < 8; ++k)
                    acc[k] = fmaf(mj, l1_4(ai[k], jr[jj]), acc[k]);
            }
        } else {
#pragma unroll
            for (int jj = 0; jj < 16; ++jj) {
                float mj = mf[j0 + jj];
#pragma unroll
                for (int k = 0; k < 8; ++k) {
                    float w = (j0 + jj > ibase + k) ? mj : 0.f;  // wave-uniform
                    acc[k] = fmaf(w, l1_4(ai[k], jr[jj]), acc[k]);
                }
            }
        }

        float tot = 0.f;
#pragma unroll
        for (int k = 0; k < 8; ++k) tot = fmaf(mf[ibase + k], acc[k], tot);
#pragma unroll
        for (int off = 32; off; off >>= 1) tot += __shfl_down(tot, off, 64);
        if (lane == 0) red[wave] = tot;
        __syncthreads();
        if (threadIdx.x == 0)
            agent_store(&edq_part[q * NT + t],
                        red[0] + red[1] + red[2] + red[3]);
    } else {
        // ---------------- xy partial ----------------
        const int bi2 = bi - QN * NT;
        const int bc = (bi2 >> 5) & 1, sc = bi2 >> 6;
        q = bi2 & 31;

        int mraw = (threadIdx.x < SN) ? M[q * SN + threadIdx.x] : 0;

        const float* Aq = A + (size_t)q * SN * EN;
        const int bbase = bc * 32 + wave * 8;
        const int s0 = sc * 16;

        float4 cb[8];
#pragma unroll
        for (int k = 0; k < 8; ++k)
            cb[k] = *(const float4*)(Cd + (size_t)(bbase + k) * EN + lane * 4);

        float4 sr[16];
#pragma unroll
        for (int ss = 0; ss < 16; ++ss)
            sr[ss] = *(const float4*)(Aq + (size_t)(s0 + ss) * EN + lane * 4);

        if (threadIdx.x < SN) mf[threadIdx.x] = (float)mraw;
        __syncthreads();

        float acc[8] = {0.f, 0.f, 0.f, 0.f, 0.f, 0.f, 0.f, 0.f};
#pragma unroll
        for (int ss = 0; ss < 16; ++ss) {
            float ms = mf[s0 + ss];
#pragma unroll
            for (int k = 0; k < 8; ++k)
                acc[k] = fmaf(ms, l1_4(sr[ss], cb[k]), acc[k]);
        }

#pragma unroll
        for (int k = 0; k < 8; ++k) {
            float t = acc[k];
#pragma unroll
            for (int off = 32; off; off >>= 1) t += __shfl_down(t, off, 64);
            if (lane == 0)
                agent_store(&xy_part[(sc * QN + q) * BN + bbase + k], t);
        }
    }

    // ---- arrival on THIS q's counter (36 contributors, 32 parallel lines) ----
    asm volatile("s_waitcnt vmcnt(0)" ::: "memory");
    __syncthreads();
    if (threadIdx.x == 0) {
        unsigned int old = __hip_atomic_fetch_add(&qcnt[q], 1u, __ATOMIC_RELAXED,
                                                  __HIP_MEMORY_SCOPE_AGENT);
        lastq = (old == (NT + 16 - 1)) ? 1u : 0u;
    }
    __syncthreads();

    if (lastq && wave == 0) {
        // ---------------- per-q closure (wave 0, 64 lanes, lane == b) ----------
        float ednum = (lane < NT) ? agent_load(&edq_part[q * NT + lane]) : 0.f;
#pragma unroll
        for (int off = 32; off; off >>= 1) ednum += __shfl_xor(ednum, off, 64);

        float xv = 0.f;
#pragma unroll
        for (int sc = 0; sc < 8; ++sc)
            xv += agent_load(&xy_part[(sc * QN + q) * BN + lane]);

        float mv = mf[lane] + mf[64 + lane];   // mask row already staged for this q
#pragma unroll
        for (int off = 32; off; off >>= 1) mv += __shfl_xor(mv, off, 64);
        float valid = fmaxf(mv, 1.f);
        float vp    = fmaxf(mv * mv, 1.f);

        // symmetry: full pair-sum = 2 * upper-triangle sum
        float score = -SCALE_F * (2.f * xv / valid - 2.f * ednum / vp);

        float mx = score;
#pragma unroll
        for (int off = 32; off; off >>= 1) mx = fmaxf(mx, __shfl_xor(mx, off, 64));
        float ex = __expf(score - mx);
#pragma unroll
        for (int off = 32; off; off >>= 1) ex += __shfl_xor(ex, off, 64);
        float lse  = mx + __logf(ex);
        float diag = __shfl(score, q, 64);

        if (lane == 0) agent_store(&loss_q[q], lse - diag);
        asm volatile("s_waitcnt vmcnt(0)" ::: "memory");

        unsigned int old2 = 0u;
        if (lane == 0)
            old2 = __hip_atomic_fetch_add(done_cnt, 1u, __ATOMIC_RELAXED,
                                          __HIP_MEMORY_SCOPE_AGENT);
        old2 = __shfl(old2, 0, 64);

        if (old2 == QN - 1u && lane == 0) {
            // ---------------- final: fixed-order sum of 32 per-q losses --------
            float s = 0.f;
#pragma unroll
            for (int qq = 0; qq < QN; ++qq) s += agent_load(&loss_q[qq]);
            out[0] = s / (float)QN;
        }
    }
}

extern "C" void kernel_launch(void* const* d_in, const int* in_sizes, int n_in,
                              void* d_out, int out_size, void* d_ws, size_t ws_size,
                              hipStream_t stream) {
    const float* A  = (const float*)d_in[0];   // anchors [Q,S,E] f32
    const float* Cd = (const float*)d_in[1];   // candidates [B,E] f32
    const int*   M  = (const int*)d_in[2];     // attention_mask [Q,S] i32
    float* out = (float*)d_out;

    float* edq_part = (float*)d_ws;                        // [QN*NT]   = 640 f
    float* xy_part  = edq_part + QN * NT;                  // [8*QN*BN] = 16384 f
    float* loss_q   = xy_part + 8 * QN * BN;               // [QN]      = 32 f
    unsigned int* qcnt     = (unsigned int*)(loss_q + QN); // [QN]
    unsigned int* done_cnt = qcnt + QN;                    // [1]

    hipMemsetAsync(qcnt, 0, (QN + 1) * sizeof(unsigned int), stream);
    kern_all<<<NB, 256, 0, stream>>>(A, Cd, M, edq_part, xy_part,
                                     loss_q, qcnt, done_cnt, out);
}